// Round 9
// baseline (842.166 us; speedup 1.0000x reference)
//
#include <hip/hip_runtime.h>
#include <hip/hip_bf16.h>

typedef __hip_bfloat16 bf16;
typedef unsigned short ushort_t;
typedef __attribute__((ext_vector_type(8))) short short8;
typedef __attribute__((ext_vector_type(4))) float float4v;

#define BSZ 32
#define TT  128
#define IC  16
#define NDIM 512
#define WS_NEED ((size_t)4 * IC * NDIM * NDIM * 2)   // 33.55 MB bf16 packed weights
#define SMEM_BYTES (32768 + 4 * 32 * 17 * 4)         // 32 KiB h + 8.5 KiB gate-exchange

// Per-(channel,16col-tile) flag words: g_flag[i*64+kt] = latest published step+1.
// SINGLE WRITER per word; all accesses sc0 sc1 (MALL-coherent). Zeroed by pack_w.
__device__ __attribute__((aligned(256))) unsigned g_flag[IC * 64];
// bf16 h exchange buffer, double-buffered by step parity. Written/read ONLY with
// sc0 sc1 (never L2-cached -> no staleness possible). 1 MB static.
__device__ __attribute__((aligned(256))) ushort_t g_hx[2][IC][BSZ * NDIM];

__device__ __forceinline__ unsigned f2bfb(float f) {
    bf16 h = __float2bfloat16(f);
    return (unsigned)*reinterpret_cast<unsigned short*>(&h);
}
// fast transcendentals: v_exp + v_rcp (1 ulp each) — error ~1e-7, far below the
// 2^-15 bf16-h quantization floor that dominates absmax.
__device__ __forceinline__ float frcp(float x) { return __builtin_amdgcn_rcpf(x); }
__device__ __forceinline__ float ftanh(float x) {
    float cx = fminf(fmaxf(x, -9.0f), 9.0f);       // tanh(9) = 1 - 3e-8
    float e  = __expf(2.0f * cx);
    return 1.0f - 2.0f * frcp(e + 1.0f);
}
__device__ __forceinline__ float fsig(float x) {
    return frcp(1.0f + __expf(-x));
}
__device__ __forceinline__ float sigf(float v) { return 1.0f / (1.0f + expf(-v)); }

// ---------------- one-time weight pack: fp32 W -> bf16 MFMA B-fragments ----
// uint4 index = ((blk*16 + kstep)*64 + lane), blk = (g*IC + i)*32 + nt16
// lane frag elems j=0..7:  W_g[i][ kstep*32 + (lane>>4)*8 + j ][ nt16*16 + (lane&15) ]
__global__ void pack_w(const float* __restrict__ Wj, const float* __restrict__ Wi,
                       const float* __restrict__ Wf, const float* __restrict__ Wo,
                       uint4* __restrict__ wpk)
{
    __shared__ float tile[NDIM][17];
    const int blk  = blockIdx.x;
    if (blk == 0) {   // reset flags; visible via end-of-kernel writeback
        for (int k = threadIdx.x; k < IC * 64; k += 256) g_flag[k] = 0u;
    }
    const int nt16 = blk & 31;
    const int i    = (blk >> 5) & 15;
    const int g    = blk >> 9;
    const float* W = (g == 0) ? Wj : (g == 1) ? Wi : (g == 2) ? Wf : Wo;
    const float* base = W + (size_t)i * NDIM * NDIM + nt16 * 16;
    const int tid = threadIdx.x;

    #pragma unroll
    for (int r = 0; r < 2; r++) {
        int n = tid + r * 256;
        const float4* p = (const float4*)(base + (size_t)n * NDIM);
        float4 v0 = p[0], v1 = p[1], v2 = p[2], v3 = p[3];
        float* d = &tile[n][0];
        d[0]=v0.x; d[1]=v0.y; d[2]=v0.z; d[3]=v0.w;
        d[4]=v1.x; d[5]=v1.y; d[6]=v1.z; d[7]=v1.w;
        d[8]=v2.x; d[9]=v2.y; d[10]=v2.z; d[11]=v2.w;
        d[12]=v3.x; d[13]=v3.y; d[14]=v3.z; d[15]=v3.w;
    }
    __syncthreads();
    #pragma unroll
    for (int p = 0; p < 4; p++) {
        int f = p * 256 + tid;
        int kstep = f >> 6, L = f & 63;
        int quad = L >> 4, col = L & 15;
        int nr = kstep * 32 + quad * 8;
        unsigned u[4];
        #pragma unroll
        for (int w = 0; w < 4; w++) {
            unsigned lo = f2bfb(tile[nr + 2 * w][col]);
            unsigned hi = f2bfb(tile[nr + 2 * w + 1][col]);
            u[w] = lo | (hi << 16);
        }
        wpk[(size_t)blk * 1024 + (size_t)kstep * 64 + L] = make_uint4(u[0], u[1], u[2], u[3]);
    }
}

// ---------------- persistent all-timesteps kernel (gate-split, 2 blocks/CU) -----
// 512 blocks, 16-col tiles, 2+ blocks/CU co-resident so two INDEPENDENT channel
// chains interleave: one block's MALL-protocol stall hides under the other's
// compute. Wave g owns gate g (16 B-frags = 64 VGPR); pre-activations are
// exchanged through a small padded LDS buffer; each thread then computes the
// full 4-gate epilogue for 2 elements. Channel map: blocks 0-255 = channels 0-7
// complete, 256-511 = channels 8-15 -> graceful serial fallback, never deadlock.
__launch_bounds__(256, 2)
__global__ void es_persist(
    const float* __restrict__ x,
    const float* __restrict__ Uj, const float* __restrict__ Ui,
    const float* __restrict__ Uf, const float* __restrict__ Uo,
    const uint4* __restrict__ wpk,
    const float* __restrict__ bj, const float* __restrict__ bi,
    const float* __restrict__ bfp, const float* __restrict__ bo,
    float* __restrict__ out)
{
    extern __shared__ unsigned char smem[];
    unsigned char* h_base = smem;                    // 32 KiB swizzled h
    float* pre_lds = (float*)(smem + 32768);         // [4][32][17] fp32 pre-activations

    const int bid = blockIdx.x;
    const int low = bid & 255;
    const int i   = (low >> 5) | ((bid >> 8) << 3);  // channel
    const int kt  = bid & 31;                        // 16-col tile
    const int tid = threadIdx.x;
    const int wid = tid >> 6, L = tid & 63;          // wid = gate owned by this wave
    const int quad = L >> 4, c15 = L & 15;

    float* hfin = out + (size_t)BSZ * TT * IC * NDIM;
    float* cfin = hfin + (size_t)BSZ * IC * NDIM;

    // ---- prologue: this wave's gate's B-fragments -> registers (64 VGPR)
    const uint4* bbase = wpk + (((size_t)wid * IC + i) * 32 + kt) * 1024 + L;
    short8 bfr[16];
    #pragma unroll
    for (int ks = 0; ks < 16; ks++) bfr[ks] = *(const short8*)(bbase + (size_t)ks * 64);

    // ---- epilogue constants: this thread owns elements (eb, n0) and (eb, n0+1)
    const int eb  = tid >> 3;                 // batch row 0..31
    const int en0 = (tid & 7) * 2;            // even local col
    const int n0  = kt * 16 + en0;            // global col
    const size_t un = (size_t)i * NDIM + n0;
    const float uja = Uj[un], ujb = Uj[un + 1];
    const float uia = Ui[un], uib = Ui[un + 1];
    const float ufa = Uf[un], ufb = Uf[un + 1];
    const float uoa = Uo[un], uob = Uo[un + 1];
    const float cja = bj[un], cjb = bj[un + 1];
    const float cia = bi[un], cib = bi[un + 1];
    const float cfa = bfp[un], cfb = bfp[un + 1];
    const float coa = bo[un], cob = bo[un + 1];
    const float a_out = 0.990049834f;          // exp(-0.01)
    const float onea  = 0.009950166f;          // 1 - exp(-0.01)

    float cc0 = 0.0f, cc1 = 0.0f;              // c-state for the 2 owned elements

    #pragma unroll 1
    for (int t = 0; t < TT; t++) {
        float xv = x[(size_t)(eb * TT + t) * IC + i];   // issue before the wait

        if (t > 0) {
            // ---- detect: lanes 0-31 of each wave poll the 32 single-writer flags
            {
                const unsigned* fp = &g_flag[(i << 6) + (L & 31)];
                bool need = (L < 32);
                unsigned v = 0;
                int spins = 0;
                while (__ballot((int)need) != 0ull) {
                    if (need) {
                        asm volatile("global_load_dword %0, %1, off sc0 sc1\n\ts_waitcnt vmcnt(0)"
                                     : "=v"(v) : "v"(fp) : "memory");
                        if (v >= (unsigned)t) need = false;
                    }
                    if (need && spins > 8) __builtin_amdgcn_s_sleep(1);
                    if (++spins > 40000) break;   // fail loud (bad data), never hang
                }
            }

            // ---- gather h(t-1) bf16: 8 coalesced sc0sc1 dwordx4 per thread
            const ushort_t* gsrc = &g_hx[(t - 1) & 1][i][0];
            float4v hg[8];
            #pragma unroll
            for (int q = 0; q < 8; q++) {
                const ushort_t* s = gsrc + (size_t)(q * 4 + wid) * NDIM + L * 8;
                asm volatile("global_load_dwordx4 %0, %1, off sc0 sc1" : "=v"(hg[q]) : "v"(s));
            }
            asm volatile("s_waitcnt vmcnt(0)" ::: "memory");
            __builtin_amdgcn_sched_barrier(0);

            // ---- swizzled LDS write (b128, conflict-free permutation per row)
            #pragma unroll
            for (int q = 0; q < 8; q++) {
                int b = q * 4 + wid;
                *(float4v*)(h_base + b * 1024 + ((L ^ (b & 7)) << 4)) = hg[q];
            }
            __syncthreads();

            // ---- MFMA: this wave computes its gate for both batch halves
            #pragma unroll
            for (int mh = 0; mh < 2; mh++) {
                const int arow = mh * 16 + c15;
                const unsigned char* aptr = h_base + arow * 1024;
                const int ax = arow & 7;
                float4v acc = {0, 0, 0, 0};
                #pragma unroll
                for (int ks = 0; ks < 16; ks++) {
                    short8 a = *(const short8*)(aptr + (((ks * 4 + quad) ^ ax) << 4));
                    acc = __builtin_amdgcn_mfma_f32_16x16x32_bf16(a, bfr[ks], acc, 0, 0, 0);
                }
                // C-layout: col = L&15, row = mh*16 + quad*4 + r
                #pragma unroll
                for (int r = 0; r < 4; r++)
                    pre_lds[wid * 544 + (mh * 16 + quad * 4 + r) * 17 + c15] = acc[r];
            }
            __syncthreads();
        }

        // ---- epilogue: 2 elements, all 4 gates from pre_lds (t=0: pre = 0)
        float p0[4], p1[4];
        #pragma unroll
        for (int g = 0; g < 4; g++) {
            p0[g] = (t > 0) ? pre_lds[g * 544 + eb * 17 + en0]     : 0.0f;
            p1[g] = (t > 0) ? pre_lds[g * 544 + eb * 17 + en0 + 1] : 0.0f;
        }
        float hprev0 = 0.0f, hprev1 = 0.0f;
        if (t > 0) {   // bf16 h read-back (coeff ~7.8e-5: bf16 is free, verified)
            hprev0 = __bfloat162float(*(const bf16*)(h_base + eb * 1024
                        + ((((n0)     >> 3) ^ (eb & 7)) << 4) + ((n0)     & 7) * 2));
            hprev1 = __bfloat162float(*(const bf16*)(h_base + eb * 1024
                        + ((((n0 + 1) >> 3) ^ (eb & 7)) << 4) + ((n0 + 1) & 7) * 2));
        }

        float hn0, hn1;
        {   // element (eb, n0)
            float jg = ftanh(p0[0] + cja + xv * uja);
            float ig = fsig (p0[1] + cia + xv * uia);
            float fg = fsig (p0[2] + cfa + xv * ufa);
            float og = fsig (p0[3] + coa + xv * uoa);
            float am1 = 7.8125e-5f * jg;         // 1 - alpha_m (exact linearization)
            float s1  = 1.5625e-4f * ig;         // 1 - ro
            float b_ad = fmaf(s1, ig - 0.1f, 0.1f);
            float Bth  = fmaf(1.8f, b_ad, 0.04f);
            float mem   = fmaf(am1, hprev0 - jg, jg) - 0.01f * Bth * ig;
            float spike = (mem - Bth) > 0.0f ? 1.0f : 0.0f;
            float mem_o = mem * a_out + onea * spike + 0.08f;
            float cn = fmaf(cc0, fg, ig * spike * mem_o);
            hn0 = og * ftanh(cn);
            cc0 = cn;
        }
        {   // element (eb, n0+1)
            float jg = ftanh(p1[0] + cjb + xv * ujb);
            float ig = fsig (p1[1] + cib + xv * uib);
            float fg = fsig (p1[2] + cfb + xv * ufb);
            float og = fsig (p1[3] + cob + xv * uob);
            float am1 = 7.8125e-5f * jg;
            float s1  = 1.5625e-4f * ig;
            float b_ad = fmaf(s1, ig - 0.1f, 0.1f);
            float Bth  = fmaf(1.8f, b_ad, 0.04f);
            float mem   = fmaf(am1, hprev1 - jg, jg) - 0.01f * Bth * ig;
            float spike = (mem - Bth) > 0.0f ? 1.0f : 0.0f;
            float mem_o = mem * a_out + onea * spike + 0.08f;
            float cn = fmaf(cc1, fg, ig * spike * mem_o);
            hn1 = og * ftanh(cn);
            cc1 = cn;
        }

        // bf16 h exchange: 2 shorts packed into ONE dword store (MALL, write-through)
        {
            ushort_t* gp = &g_hx[t & 1][i][(size_t)eb * NDIM + n0];
            unsigned hb = f2bfb(hn0) | (f2bfb(hn1) << 16);
            asm volatile("global_store_dword %0, %1, off sc0 sc1" :: "v"(gp), "v"(hb) : "memory");
        }
        // fp32 h for the harness output: plain cached float2 store
        {
            float* op = out + ((size_t)(eb * TT + t) * IC + i) * NDIM + n0;
            op[0] = hn0; op[1] = hn1;
        }
        if (t == TT - 1) {
            size_t sidx = ((size_t)eb * IC + i) * NDIM + n0;
            cfin[sidx] = cc0; cfin[sidx + 1] = cc1;
            hfin[sidx] = hn0; hfin[sidx + 1] = hn1;
        }

        // ---- publish h(t): drain stores (MALL ack), join, set flag word
        if (t < TT - 1) {
            asm volatile("s_waitcnt vmcnt(0)" ::: "memory");
            __syncthreads();
            if (tid == 0) {
                unsigned tv = (unsigned)(t + 1);
                const unsigned* fp = &g_flag[(i << 6) + kt];
                asm volatile("global_store_dword %0, %1, off sc0 sc1" :: "v"(fp), "v"(tv) : "memory");
            }
        }
    }
}

// ---------------- fallback (proven R5 path, used only if ws too small) ----
#define KT 32
#define NC 64
__launch_bounds__(256)
__global__ void step_kernel_valu(int t,
    const float* __restrict__ x,
    const float* __restrict__ Uj, const float* __restrict__ Ui, const float* __restrict__ Uf, const float* __restrict__ Uo,
    const float* __restrict__ Wj, const float* __restrict__ Wi, const float* __restrict__ Wf, const float* __restrict__ Wo,
    const float* __restrict__ bj, const float* __restrict__ bi, const float* __restrict__ bfp, const float* __restrict__ bo,
    float* __restrict__ out)
{
    __shared__ float w_lds[NC][KT * 4 + 4];
    __shared__ float h_lds[NC][BSZ + 4];
    const int i = blockIdx.x, k0 = blockIdx.y * KT, tid = threadIdx.x;
    const int kl = tid & 31, bg = tid >> 5, kg = k0 + kl;
    float* hfin = out + (size_t)BSZ * TT * IC * NDIM;
    float* cfin = hfin + (size_t)BSZ * IC * NDIM;
    float acc[4][4];
    {
        size_t uidx = (size_t)i * NDIM + kg;
        float u0 = Uj[uidx], u1 = Ui[uidx], u2 = Uf[uidx], u3 = Uo[uidx];
        float c0 = bj[uidx], c1 = bi[uidx], c2 = bfp[uidx], c3 = bo[uidx];
        #pragma unroll
        for (int j = 0; j < 4; j++) {
            int b = bg * 4 + j;
            float xv = x[(size_t)(b * TT + t) * IC + i];
            acc[0][j] = c0 + xv * u0; acc[1][j] = c1 + xv * u1;
            acc[2][j] = c2 + xv * u2; acc[3][j] = c3 + xv * u3;
        }
    }
    if (t > 0) {
        for (int n0 = 0; n0 < NDIM; n0 += NC) {
            __syncthreads();
            {
                int g = tid >> 6, nn = tid & 63;
                const float* Wp = (g == 0) ? Wj : (g == 1) ? Wi : (g == 2) ? Wf : Wo;
                const float4* p = (const float4*)(Wp + ((size_t)i * NDIM + (size_t)(n0 + nn)) * NDIM + k0);
                #pragma unroll
                for (int q = 0; q < 8; q++) {
                    float4 v = p[q];
                    w_lds[nn][(q * 4 + 0) * 4 + g] = v.x; w_lds[nn][(q * 4 + 1) * 4 + g] = v.y;
                    w_lds[nn][(q * 4 + 2) * 4 + g] = v.z; w_lds[nn][(q * 4 + 3) * 4 + g] = v.w;
                }
            }
            {
                int b = tid >> 3, nb = (tid & 7) * 8;
                const float4* ph = (const float4*)(out + ((size_t)(b * TT + (t - 1)) * IC + i) * NDIM + n0 + nb);
                float4 h0 = ph[0], h1 = ph[1];
                h_lds[nb + 0][b] = h0.x; h_lds[nb + 1][b] = h0.y; h_lds[nb + 2][b] = h0.z; h_lds[nb + 3][b] = h0.w;
                h_lds[nb + 4][b] = h1.x; h_lds[nb + 5][b] = h1.y; h_lds[nb + 6][b] = h1.z; h_lds[nb + 7][b] = h1.w;
            }
            __syncthreads();
            #pragma unroll 8
            for (int nn = 0; nn < NC; nn++) {
                float4 wv = *(const float4*)&w_lds[nn][kl * 4];
                float4 hv = *(const float4*)&h_lds[nn][bg * 4];
                acc[0][0] += hv.x * wv.x; acc[1][0] += hv.x * wv.y; acc[2][0] += hv.x * wv.z; acc[3][0] += hv.x * wv.w;
                acc[0][1] += hv.y * wv.x; acc[1][1] += hv.y * wv.y; acc[2][1] += hv.y * wv.z; acc[3][1] += hv.y * wv.w;
                acc[0][2] += hv.z * wv.x; acc[1][2] += hv.z * wv.y; acc[2][2] += hv.z * wv.z; acc[3][2] += hv.z * wv.w;
                acc[0][3] += hv.w * wv.x; acc[1][3] += hv.w * wv.y; acc[2][3] += hv.w * wv.z; acc[3][3] += hv.w * wv.w;
            }
        }
    }
    const float a_out = 0.990049834f;
    #pragma unroll
    for (int j = 0; j < 4; j++) {
        int b = bg * 4 + j;
        size_t sidx = ((size_t)b * IC + i) * NDIM + kg;
        float jg = tanhf(acc[0][j]), ig = sigf(acc[1][j]), fg = sigf(acc[2][j]), og = sigf(acc[3][j]);
        float alpha_m = expf(-7.8125e-5f * jg);
        float ro = expf(-1.5625e-4f * ig);
        float b_ad = ro * 0.1f + (1.0f - ro) * ig;
        float Bth = 0.04f + 1.8f * b_ad;
        float hprev = 0.0f, cprev = 0.0f;
        if (t > 0) { hprev = out[((size_t)(b * TT + (t - 1)) * IC + i) * NDIM + kg]; cprev = cfin[sidx]; }
        float mem = jg * alpha_m + (1.0f - alpha_m) * hprev - Bth * ig * 0.01f;
        float spike = (mem - Bth) > 0.0f ? 1.0f : 0.0f;
        float mem_o = mem * a_out + (1.0f - a_out) * spike + 0.08f;
        float cn = cprev * fg + ig * spike * mem_o;
        float hn = og * tanhf(cn);
        cfin[sidx] = cn;
        out[((size_t)(b * TT + t) * IC + i) * NDIM + kg] = hn;
        if (t == TT - 1) hfin[sidx] = hn;
    }
}

extern "C" void kernel_launch(void* const* d_in, const int* in_sizes, int n_in,
                              void* d_out, int out_size, void* d_ws, size_t ws_size,
                              hipStream_t stream) {
    const float* x   = (const float*)d_in[0];
    const float* Uj  = (const float*)d_in[1];
    const float* Ui_ = (const float*)d_in[2];
    const float* Uf  = (const float*)d_in[3];
    const float* Uo  = (const float*)d_in[4];
    const float* Wj  = (const float*)d_in[5];
    const float* Wi  = (const float*)d_in[6];
    const float* Wf  = (const float*)d_in[7];
    const float* Wo  = (const float*)d_in[8];
    const float* bj  = (const float*)d_in[9];
    const float* bi_ = (const float*)d_in[10];
    const float* bf_ = (const float*)d_in[11];
    const float* bo  = (const float*)d_in[12];
    float* out = (float*)d_out;

    if (ws_size >= WS_NEED) {
        static bool attr_set = false;
        if (!attr_set) {   // opt-in to >48KB dynamic LDS (host-side, not captured)
            (void)hipFuncSetAttribute((const void*)es_persist,
                                      hipFuncAttributeMaxDynamicSharedMemorySize, SMEM_BYTES);
            attr_set = true;
        }
        pack_w<<<dim3(2048), dim3(256), 0, stream>>>(Wj, Wi, Wf, Wo, (uint4*)d_ws);
        es_persist<<<dim3(512), dim3(256), SMEM_BYTES, stream>>>(
            x, Uj, Ui_, Uf, Uo, (const uint4*)d_ws, bj, bi_, bf_, bo, out);
    } else {
        for (int t = 0; t < TT; t++) {
            step_kernel_valu<<<dim3(IC, NDIM / KT), dim3(256), 0, stream>>>(
                t, x, Uj, Ui_, Uf, Uo, Wj, Wi, Wf, Wo, bj, bi_, bf_, bo, out);
        }
    }
}

// Round 10
// 705.078 us; speedup vs baseline: 1.1944x; 1.1944x over previous
//
#include <hip/hip_runtime.h>
#include <hip/hip_bf16.h>

typedef __hip_bfloat16 bf16;
typedef unsigned short ushort_t;
typedef __attribute__((ext_vector_type(8))) short short8;
typedef __attribute__((ext_vector_type(4))) float float4v;

#define BSZ 32
#define TT  128
#define IC  16
#define NDIM 512
#define WS_NEED ((size_t)4 * IC * NDIM * NDIM * 2)   // 33.55 MB bf16 packed weights
#define SMEM_BYTES 131072                            // force 1 block/CU (32K h + 2.5K hx used)

// Per-(channel,tile) flag words: g_flag[i*64+kt] = latest published step+1.
// SINGLE WRITER per word; all accesses sc0 sc1 (MALL-coherent). Zeroed by pack_w.
__device__ __attribute__((aligned(256))) unsigned g_flag[IC * 64];
// bf16 h exchange, double-buffered by parity, TILE-MAJOR: [p][i][kt][b][32cols].
// Producer tile = 2 KB contiguous -> dense coalesced stores; gather fully contiguous.
__device__ __attribute__((aligned(256))) ushort_t g_hx[2][IC][BSZ * NDIM];

__device__ __forceinline__ unsigned f2bfb(float f) {
    bf16 h = __float2bfloat16(f);
    return (unsigned)*reinterpret_cast<unsigned short*>(&h);
}
// fast transcendentals: v_exp + v_rcp (1 ulp each) — error ~1e-7, far below the
// 2^-15 bf16-h quantization floor that dominates absmax.
__device__ __forceinline__ float frcp(float x) { return __builtin_amdgcn_rcpf(x); }
__device__ __forceinline__ float ftanh(float x) {
    float cx = fminf(fmaxf(x, -9.0f), 9.0f);       // tanh(9) = 1 - 3e-8
    float e  = __expf(2.0f * cx);
    return 1.0f - 2.0f * frcp(e + 1.0f);
}
__device__ __forceinline__ float fsig(float x) {
    return frcp(1.0f + __expf(-x));
}
__device__ __forceinline__ float sigf(float v) { return 1.0f / (1.0f + expf(-v)); }

// ---------------- one-time weight pack: fp32 W -> bf16 MFMA B-fragments ----
// uint4 index = ((blk*16 + kstep)*64 + lane), blk = (g*IC + i)*32 + nt16
// lane frag elems j=0..7:  W_g[i][ kstep*32 + (lane>>4)*8 + j ][ nt16*16 + (lane&15) ]
__global__ void pack_w(const float* __restrict__ Wj, const float* __restrict__ Wi,
                       const float* __restrict__ Wf, const float* __restrict__ Wo,
                       uint4* __restrict__ wpk)
{
    __shared__ float tile[NDIM][17];
    const int blk  = blockIdx.x;
    if (blk == 0) {   // reset flags; visible via end-of-kernel writeback
        for (int k = threadIdx.x; k < IC * 64; k += 256) g_flag[k] = 0u;
    }
    const int nt16 = blk & 31;
    const int i    = (blk >> 5) & 15;
    const int g    = blk >> 9;
    const float* W = (g == 0) ? Wj : (g == 1) ? Wi : (g == 2) ? Wf : Wo;
    const float* base = W + (size_t)i * NDIM * NDIM + nt16 * 16;
    const int tid = threadIdx.x;

    #pragma unroll
    for (int r = 0; r < 2; r++) {
        int n = tid + r * 256;
        const float4* p = (const float4*)(base + (size_t)n * NDIM);
        float4 v0 = p[0], v1 = p[1], v2 = p[2], v3 = p[3];
        float* d = &tile[n][0];
        d[0]=v0.x; d[1]=v0.y; d[2]=v0.z; d[3]=v0.w;
        d[4]=v1.x; d[5]=v1.y; d[6]=v1.z; d[7]=v1.w;
        d[8]=v2.x; d[9]=v2.y; d[10]=v2.z; d[11]=v2.w;
        d[12]=v3.x; d[13]=v3.y; d[14]=v3.z; d[15]=v3.w;
    }
    __syncthreads();
    #pragma unroll
    for (int p = 0; p < 4; p++) {
        int f = p * 256 + tid;
        int kstep = f >> 6, L = f & 63;
        int quad = L >> 4, col = L & 15;
        int nr = kstep * 32 + quad * 8;
        unsigned u[4];
        #pragma unroll
        for (int w = 0; w < 4; w++) {
            unsigned lo = f2bfb(tile[nr + 2 * w][col]);
            unsigned hi = f2bfb(tile[nr + 2 * w + 1][col]);
            u[w] = lo | (hi << 16);
        }
        wpk[(size_t)blk * 1024 + (size_t)kstep * 64 + L] = make_uint4(u[0], u[1], u[2], u[3]);
    }
}

// ---------------- persistent all-timesteps kernel (R8 base + dense exchange) ----
// 256 blocks, 1 block/CU. Block = (channel i = bid&15, tile kt = bid>>4).
// Weights in REGISTERS all 128 steps. Exchange: bf16 tile-major g_hx, sc0 sc1
// only; dense producer stores via 2.5 KB LDS transpose; single-writer flags.
__launch_bounds__(256, 1)
__global__ void es_persist(
    const float* __restrict__ x,
    const float* __restrict__ Uj, const float* __restrict__ Ui,
    const float* __restrict__ Uf, const float* __restrict__ Uo,
    const uint4* __restrict__ wpk,
    const float* __restrict__ bj, const float* __restrict__ bi,
    const float* __restrict__ bfp, const float* __restrict__ bo,
    float* __restrict__ out)
{
    extern __shared__ unsigned char smem[];
    unsigned char* h_base = smem;              // 32 KiB: row b at b*1024 B, chunk c at ((c^(b&7))<<4)
    unsigned char* hx     = smem + 32768;      // [32 rows][stride 80 B]: own-tile hn bf16 transpose

    const int bid = blockIdx.x;
    const int i   = bid & 15;                  // channel
    const int kt  = bid >> 4;                  // 32-col tile
    const int tid = threadIdx.x;
    const int wid = tid >> 6, L = tid & 63;
    const int quad = L >> 4, c15 = L & 15;
    const int ntl  = wid & 1;                  // local 16-col tile
    const int nt16 = kt * 2 + ntl;
    const int Mh   = (wid >> 1) * 16;          // batch half

    float* hfin = out + (size_t)BSZ * TT * IC * NDIM;
    float* cfin = hfin + (size_t)BSZ * IC * NDIM;

    // ---- prologue: this wave's B-fragments -> REGISTERS (once, stays all 128 steps)
    const size_t gstride = (size_t)IC * 32 * 1024;                    // uint4s per gate
    const uint4* bbase = wpk + ((size_t)i * 32 + nt16) * 1024 + L;
    short8 bfr0[16], bfr1[16], bfr2[16], bfr3[16];
    #pragma unroll
    for (int ks = 0; ks < 16; ks++) bfr0[ks] = *(const short8*)(bbase + (size_t)ks * 64);
    #pragma unroll
    for (int ks = 0; ks < 16; ks++) bfr1[ks] = *(const short8*)(bbase + gstride + (size_t)ks * 64);
    #pragma unroll
    for (int ks = 0; ks < 16; ks++) bfr2[ks] = *(const short8*)(bbase + 2 * gstride + (size_t)ks * 64);
    #pragma unroll
    for (int ks = 0; ks < 16; ks++) bfr3[ks] = *(const short8*)(bbase + 3 * gstride + (size_t)ks * 64);

    // ---- loop-invariant per-lane scalars
    const int n = nt16 * 16 + c15;             // global col owned in epilogue
    const int nl = ntl * 16 + c15;             // col within own 32-col tile
    const size_t un = (size_t)i * NDIM + n;
    const float u0 = Uj[un], u1 = Ui[un], u2 = Uf[un], u3 = Uo[un];
    const float c0 = bj[un], c1 = bi[un], c2 = bfp[un], c3 = bo[un];
    const float a_out = 0.990049834f;          // exp(-0.01)
    const float onea  = 0.009950166f;          // 1 - exp(-0.01)

    float cc[4] = {0.f, 0.f, 0.f, 0.f};        // c-state in registers across all steps

    // gather mapping (tile-major): load l covers bytes [l*4096 + tid*16, +16)
    const int gb  = (tid >> 2) & 31;           // LDS dest row for gather chunk
    const int gb7 = gb & 7;
    const int tkb = (tid >> 7) * 4 + (tid & 3);   // cidx base: (2l + tid>>7)*4 + (tid&3)

    #pragma unroll 1
    for (int t = 0; t < TT; t++) {
        float4v acc0 = {0,0,0,0}, acc1 = {0,0,0,0}, acc2 = {0,0,0,0}, acc3 = {0,0,0,0};

        // x loads depend on no other block: issue before the wait
        float xv[4];
        #pragma unroll
        for (int r = 0; r < 4; r++)
            xv[r] = x[(size_t)((Mh + quad * 4 + r) * TT + t) * IC + i];

        if (t > 0) {
            // ---- detect: lanes 0-15 of each wave poll 16 single-writer flags (MALL)
            {
                const unsigned* fp = &g_flag[(i << 6) + (L & 15)];
                bool need = (L < 16);
                unsigned v = 0;
                int spins = 0;
                while (__ballot((int)need) != 0ull) {
                    if (need) {
                        asm volatile("global_load_dword %0, %1, off sc0 sc1\n\ts_waitcnt vmcnt(0)"
                                     : "=v"(v) : "v"(fp) : "memory");
                        if (v >= (unsigned)t) need = false;
                    }
                    if (need && spins > 64) __builtin_amdgcn_s_sleep(1);
                    if (++spins > 40000) break;   // fail loud (bad data), never hang
                }
            }

            // ---- gather h(t-1): 8 fully-contiguous sc0sc1 dwordx4 per thread
            const ushort_t* gsrc = &g_hx[(t - 1) & 1][i][0];
            float4v hg[8];
            #pragma unroll
            for (int l = 0; l < 8; l++) {
                const ushort_t* s = gsrc + (size_t)l * 2048 + tid * 8;
                asm volatile("global_load_dwordx4 %0, %1, off sc0 sc1" : "=v"(hg[l]) : "v"(s));
            }
            asm volatile("s_waitcnt vmcnt(0)" ::: "memory");
            __builtin_amdgcn_sched_barrier(0);

            // ---- scatter to swizzled LDS (b128, 8 lanes/bank-quad = conflict floor)
            #pragma unroll
            for (int l = 0; l < 8; l++) {
                int cidx = l * 8 + tkb;
                *(float4v*)(h_base + gb * 1024 + ((cidx ^ gb7) << 4)) = hg[l];
            }
            __syncthreads();

            // ---- MFMA: A from swizzled h LDS, B resident in registers
            const int arow = Mh + c15;
            const unsigned char* aptr = h_base + arow * 1024;
            const int ax = arow & 7;
            #pragma unroll
            for (int ks = 0; ks < 16; ks++) {
                short8 a = *(const short8*)(aptr + (((ks * 4 + quad) ^ ax) << 4));
                acc0 = __builtin_amdgcn_mfma_f32_16x16x32_bf16(a, bfr0[ks], acc0, 0, 0, 0);
                acc1 = __builtin_amdgcn_mfma_f32_16x16x32_bf16(a, bfr1[ks], acc1, 0, 0, 0);
                acc2 = __builtin_amdgcn_mfma_f32_16x16x32_bf16(a, bfr2[ks], acc2, 0, 0, 0);
                acc3 = __builtin_amdgcn_mfma_f32_16x16x32_bf16(a, bfr3[ks], acc3, 0, 0, 0);
            }
        }

        // ---- epilogue: fast-math gates; hn -> registers + LDS transpose buffer
        float hnv[4];
        #pragma unroll
        for (int r = 0; r < 4; r++) {
            const int b = Mh + quad * 4 + r;    // C-layout row

            float jg = ftanh(acc0[r] + c0 + xv[r] * u0);
            float ig = fsig (acc1[r] + c1 + xv[r] * u1);
            float fg = fsig (acc2[r] + c2 + xv[r] * u2);
            float og = fsig (acc3[r] + c3 + xv[r] * u3);

            float am1 = 7.8125e-5f * jg;        // 1 - alpha_m (exact linearization)
            float s1  = 1.5625e-4f * ig;        // 1 - ro      (exact linearization)
            float b_ad = fmaf(s1, ig - 0.1f, 0.1f);
            float Bth  = fmaf(1.8f, b_ad, 0.04f);

            float hprev = 0.0f;
            if (t > 0)   // coeff am1 ~7.8e-5: bf16 h is free (same as verified path)
                hprev = __bfloat162float(*(const bf16*)(h_base + b * 1024
                            + (((n >> 3) ^ (b & 7)) << 4) + (n & 7) * 2));

            float mem   = fmaf(am1, hprev - jg, jg) - 0.01f * Bth * ig;
            float spike = (mem - Bth) > 0.0f ? 1.0f : 0.0f;
            float mem_o = mem * a_out + onea * spike + 0.08f;

            float cn = fmaf(cc[r], fg, ig * spike * mem_o);
            float hn = og * ftanh(cn);
            cc[r] = cn; hnv[r] = hn;

            // own-tile bf16 transpose in LDS (2.5 KB, stride 80 B)
            *(ushort_t*)(hx + b * 80 + nl * 2) = (ushort_t)f2bfb(hn);
        }

        // ---- publish h(t): dense coalesced tile store, drain, flag
        if (t < TT - 1) {
            __syncthreads();                    // hx transpose complete
            if (tid < 128) {                    // 128 x 16 B = whole 2 KB tile, 1 KB/wave-instr
                int row = tid >> 2, cg = tid & 3;
                float4v v = *(const float4v*)(hx + row * 80 + cg * 16);
                ushort_t* gp = &g_hx[t & 1][i][0] + kt * 1024 + row * 32 + cg * 8;
                asm volatile("global_store_dwordx4 %0, %1, off sc0 sc1" :: "v"(gp), "v"(v) : "memory");
            }
            asm volatile("s_waitcnt vmcnt(0)" ::: "memory");
            __syncthreads();
            if (tid == 0) {
                unsigned tv = (unsigned)(t + 1);
                const unsigned* fp = &g_flag[(i << 6) + kt];
                asm volatile("global_store_dword %0, %1, off sc0 sc1" :: "v"(fp), "v"(tv) : "memory");
            }
        }

        // ---- deferred harness stores (off the drain path; overlap next detect)
        #pragma unroll
        for (int r = 0; r < 4; r++) {
            const int b = Mh + quad * 4 + r;
            out[((size_t)(b * TT + t) * IC + i) * NDIM + n] = hnv[r];
            if (t == TT - 1) {
                size_t sidx = ((size_t)b * IC + i) * NDIM + n;
                cfin[sidx] = cc[r];
                hfin[sidx] = hnv[r];
            }
        }
    }
}

// ---------------- fallback (proven R5 path, used only if ws too small) ----
#define KT 32
#define NC 64
__launch_bounds__(256)
__global__ void step_kernel_valu(int t,
    const float* __restrict__ x,
    const float* __restrict__ Uj, const float* __restrict__ Ui, const float* __restrict__ Uf, const float* __restrict__ Uo,
    const float* __restrict__ Wj, const float* __restrict__ Wi, const float* __restrict__ Wf, const float* __restrict__ Wo,
    const float* __restrict__ bj, const float* __restrict__ bi, const float* __restrict__ bfp, const float* __restrict__ bo,
    float* __restrict__ out)
{
    __shared__ float w_lds[NC][KT * 4 + 4];
    __shared__ float h_lds[NC][BSZ + 4];
    const int i = blockIdx.x, k0 = blockIdx.y * KT, tid = threadIdx.x;
    const int kl = tid & 31, bg = tid >> 5, kg = k0 + kl;
    float* hfin = out + (size_t)BSZ * TT * IC * NDIM;
    float* cfin = hfin + (size_t)BSZ * IC * NDIM;
    float acc[4][4];
    {
        size_t uidx = (size_t)i * NDIM + kg;
        float u0 = Uj[uidx], u1 = Ui[uidx], u2 = Uf[uidx], u3 = Uo[uidx];
        float c0 = bj[uidx], c1 = bi[uidx], c2 = bfp[uidx], c3 = bo[uidx];
        #pragma unroll
        for (int j = 0; j < 4; j++) {
            int b = bg * 4 + j;
            float xv = x[(size_t)(b * TT + t) * IC + i];
            acc[0][j] = c0 + xv * u0; acc[1][j] = c1 + xv * u1;
            acc[2][j] = c2 + xv * u2; acc[3][j] = c3 + xv * u3;
        }
    }
    if (t > 0) {
        for (int n0 = 0; n0 < NDIM; n0 += NC) {
            __syncthreads();
            {
                int g = tid >> 6, nn = tid & 63;
                const float* Wp = (g == 0) ? Wj : (g == 1) ? Wi : (g == 2) ? Wf : Wo;
                const float4* p = (const float4*)(Wp + ((size_t)i * NDIM + (size_t)(n0 + nn)) * NDIM + k0);
                #pragma unroll
                for (int q = 0; q < 8; q++) {
                    float4 v = p[q];
                    w_lds[nn][(q * 4 + 0) * 4 + g] = v.x; w_lds[nn][(q * 4 + 1) * 4 + g] = v.y;
                    w_lds[nn][(q * 4 + 2) * 4 + g] = v.z; w_lds[nn][(q * 4 + 3) * 4 + g] = v.w;
                }
            }
            {
                int b = tid >> 3, nb = (tid & 7) * 8;
                const float4* ph = (const float4*)(out + ((size_t)(b * TT + (t - 1)) * IC + i) * NDIM + n0 + nb);
                float4 h0 = ph[0], h1 = ph[1];
                h_lds[nb + 0][b] = h0.x; h_lds[nb + 1][b] = h0.y; h_lds[nb + 2][b] = h0.z; h_lds[nb + 3][b] = h0.w;
                h_lds[nb + 4][b] = h1.x; h_lds[nb + 5][b] = h1.y; h_lds[nb + 6][b] = h1.z; h_lds[nb + 7][b] = h1.w;
            }
            __syncthreads();
            #pragma unroll 8
            for (int nn = 0; nn < NC; nn++) {
                float4 wv = *(const float4*)&w_lds[nn][kl * 4];
                float4 hv = *(const float4*)&h_lds[nn][bg * 4];
                acc[0][0] += hv.x * wv.x; acc[1][0] += hv.x * wv.y; acc[2][0] += hv.x * wv.z; acc[3][0] += hv.x * wv.w;
                acc[0][1] += hv.y * wv.x; acc[1][1] += hv.y * wv.y; acc[2][1] += hv.y * wv.z; acc[3][1] += hv.y * wv.w;
                acc[0][2] += hv.z * wv.x; acc[1][2] += hv.z * wv.y; acc[2][2] += hv.z * wv.z; acc[3][2] += hv.z * wv.w;
                acc[0][3] += hv.w * wv.x; acc[1][3] += hv.w * wv.y; acc[2][3] += hv.w * wv.z; acc[3][3] += hv.w * wv.w;
            }
        }
    }
    const float a_out = 0.990049834f;
    #pragma unroll
    for (int j = 0; j < 4; j++) {
        int b = bg * 4 + j;
        size_t sidx = ((size_t)b * IC + i) * NDIM + kg;
        float jg = tanhf(acc[0][j]), ig = sigf(acc[1][j]), fg = sigf(acc[2][j]), og = sigf(acc[3][j]);
        float alpha_m = expf(-7.8125e-5f * jg);
        float ro = expf(-1.5625e-4f * ig);
        float b_ad = ro * 0.1f + (1.0f - ro) * ig;
        float Bth = 0.04f + 1.8f * b_ad;
        float hprev = 0.0f, cprev = 0.0f;
        if (t > 0) { hprev = out[((size_t)(b * TT + (t - 1)) * IC + i) * NDIM + kg]; cprev = cfin[sidx]; }
        float mem = jg * alpha_m + (1.0f - alpha_m) * hprev - Bth * ig * 0.01f;
        float spike = (mem - Bth) > 0.0f ? 1.0f : 0.0f;
        float mem_o = mem * a_out + (1.0f - a_out) * spike + 0.08f;
        float cn = cprev * fg + ig * spike * mem_o;
        float hn = og * tanhf(cn);
        cfin[sidx] = cn;
        out[((size_t)(b * TT + t) * IC + i) * NDIM + kg] = hn;
        if (t == TT - 1) hfin[sidx] = hn;
    }
}

extern "C" void kernel_launch(void* const* d_in, const int* in_sizes, int n_in,
                              void* d_out, int out_size, void* d_ws, size_t ws_size,
                              hipStream_t stream) {
    const float* x   = (const float*)d_in[0];
    const float* Uj  = (const float*)d_in[1];
    const float* Ui_ = (const float*)d_in[2];
    const float* Uf  = (const float*)d_in[3];
    const float* Uo  = (const float*)d_in[4];
    const float* Wj  = (const float*)d_in[5];
    const float* Wi  = (const float*)d_in[6];
    const float* Wf  = (const float*)d_in[7];
    const float* Wo  = (const float*)d_in[8];
    const float* bj  = (const float*)d_in[9];
    const float* bi_ = (const float*)d_in[10];
    const float* bf_ = (const float*)d_in[11];
    const float* bo  = (const float*)d_in[12];
    float* out = (float*)d_out;

    if (ws_size >= WS_NEED) {
        static bool attr_set = false;
        if (!attr_set) {   // opt-in to 128 KiB dynamic LDS (host-side, not captured)
            (void)hipFuncSetAttribute((const void*)es_persist,
                                      hipFuncAttributeMaxDynamicSharedMemorySize, SMEM_BYTES);
            attr_set = true;
        }
        pack_w<<<dim3(2048), dim3(256), 0, stream>>>(Wj, Wi, Wf, Wo, (uint4*)d_ws);
        es_persist<<<dim3(256), dim3(256), SMEM_BYTES, stream>>>(
            x, Uj, Ui_, Uf, Uo, (const uint4*)d_ws, bj, bi_, bf_, bo, out);
    } else {
        for (int t = 0; t < TT; t++) {
            step_kernel_valu<<<dim3(IC, NDIM / KT), dim3(256), 0, stream>>>(
                t, x, Uj, Ui_, Uf, Uo, Wj, Wi, Wf, Wo, bj, bi_, bf_, bo, out);
        }
    }
}